// Round 3
// baseline (235.456 us; speedup 1.0000x reference)
//
#include <hip/hip_runtime.h>

#define NCH 5  // thermostat chain length (C) — fixed by the problem

// ---------------------------------------------------------------------------
// Fused single-pass NHC kernel, non-cooperative, HANG-PROOF.
//
// History: round 1 (hipLaunchCooperativeKernel) was silently dropped by the
// harness -> zero outputs. Round 2 (unbounded spin on cross-block signals)
// hung the GPU twice -> co-residency of all 1024 blocks is NOT guaranteed
// here. This version keeps the fused design but every loop is bounded:
//
//  Phase A: each thread loads 12 float4 of mom (16 atoms) + 4 float4 of mas,
//           KEEPS mom in registers, deterministic block reduce, publishes the
//           block partial as (bits, ~bits) at agent scope. Poison-proof: no
//           32-bit word equals its own complement, so uninitialized workspace
//           can never validate; replay-stale signals are bit-identical
//           (inputs are restored each iteration).
//  Phase B: wave-0 lanes 0..31 poll the batch's 32 signals with a BOUNDED
//           loop (4096 iters ~ 0.7 ms >> legitimate ~30 us wait). On timeout
//           a lane recomputes that block's partial itself from global memory
//           (always possible: inputs are read-only) -> deadlock-free by
//           construction. Fixed butterfly sum; lane 0 runs the 14-substep
//           SY chain; block x==0 writes pos_nhc/mom_nhc; scale via LDS.
//  Phase C: scale the register-held mom and store.
//
// Traffic: mom read once + mas read + mom written = ~117 MB vs ~167 MB for
// the two-kernel version, and one launch instead of two.
// ---------------------------------------------------------------------------
__global__ __launch_bounds__(256, 4) void nhc_fused(
    const float* __restrict__ mom, const float* __restrict__ mas,
    const float* __restrict__ kbt, const float* __restrict__ dtm,
    const float* __restrict__ pos_nhc, const float* __restrict__ mom_nhc,
    const float* __restrict__ mas_nhc, const float* __restrict__ stp,
    float* __restrict__ out_mom, float* __restrict__ out_posnhc,
    float* __restrict__ out_momnhc,
    unsigned int* __restrict__ sig_part, unsigned int* __restrict__ sig_chk,
    int n4_per_batch, int nm4_per_batch, float dof)
{
    const int bid = blockIdx.x;            // 0..1023, batch-major
    const int b   = bid >> 5;              // batch index
    const int x   = bid & 31;              // block within batch
    const int g   = x * blockDim.x + threadIdx.x;  // thread in batch 0..8191

    // ---- Phase A: load + KE partial (thread-contiguous 16-atom slice) ----
    const float4* mom4 = (const float4*)mom + (size_t)b * n4_per_batch + 12 * (size_t)g;
    const float4* mas4 = (const float4*)mas + (size_t)b * nm4_per_batch + 4 * (size_t)g;

    float4 P[12];
    float ke = 0.0f;
    #pragma unroll
    for (int q = 0; q < 4; ++q) {
        const float4 m = mas4[q];
        const float4 a = mom4[3 * q + 0];
        const float4 c = mom4[3 * q + 1];
        const float4 d = mom4[3 * q + 2];
        P[3 * q + 0] = a; P[3 * q + 1] = c; P[3 * q + 2] = d;
        ke += (a.x * a.x + a.y * a.y + a.z * a.z) / m.x
            + (a.w * a.w + c.x * c.x + c.y * c.y) / m.y
            + (c.z * c.z + c.w * c.w + d.x * d.x) / m.z
            + (d.y * d.y + d.z * d.z + d.w * d.w) / m.w;
    }

    // deterministic block reduce: fixed butterfly + fixed wave order
    #pragma unroll
    for (int off = 32; off > 0; off >>= 1) ke += __shfl_down(ke, off, 64);
    __shared__ float lds[4];
    __shared__ float s_scale;
    const int lane = threadIdx.x & 63, wv = threadIdx.x >> 6;
    if (lane == 0) lds[wv] = ke;
    __syncthreads();
    if (threadIdx.x == 0) {
        const float pblk = lds[0] + lds[1] + lds[2] + lds[3];
        const unsigned int pb = __float_as_uint(pblk);
        __hip_atomic_store(&sig_part[bid], pb, __ATOMIC_RELAXED,
                           __HIP_MEMORY_SCOPE_AGENT);
        __hip_atomic_store(&sig_chk[bid], ~pb, __ATOMIC_RELEASE,
                           __HIP_MEMORY_SCOPE_AGENT);
    }

    // ---- Phase B: gather batch partials (bounded), redundant chain ----
    if (threadIdx.x < 64) {
        float t = 0.0f;
        if (threadIdx.x < 32) {
            const int j = threadIdx.x;         // which block's partial
            const int i = b * 32 + j;
            unsigned int pb = 0u;
            bool got = false;
            for (int it = 0; it < 4096; ++it) {   // bounded: ~0.7 ms max
                const unsigned int ck =
                    __hip_atomic_load(&sig_chk[i], __ATOMIC_ACQUIRE,
                                      __HIP_MEMORY_SCOPE_AGENT);
                pb = __hip_atomic_load(&sig_part[i], __ATOMIC_RELAXED,
                                       __HIP_MEMORY_SCOPE_AGENT);
                if (ck == ~pb) { got = true; break; }
                __builtin_amdgcn_s_sleep(2);
            }
            if (got) {
                t = __uint_as_float(pb);
            } else {
                // self-service fallback: recompute block j's partial from
                // the read-only inputs. Correct regardless of scheduling;
                // ulp-level order difference vs the block reduce is far
                // below the output tolerance.
                const float4* bm4 = (const float4*)mom +
                    (size_t)b * n4_per_batch + (size_t)j * 3072;
                const float4* bs4 = (const float4*)mas +
                    (size_t)b * nm4_per_batch + (size_t)j * 1024;
                float acc = 0.0f;
                for (int mi = 0; mi < 1024; ++mi) {
                    const float4 m = bs4[mi];
                    const float4 a = bm4[3 * mi + 0];
                    const float4 c = bm4[3 * mi + 1];
                    const float4 d = bm4[3 * mi + 2];
                    acc += (a.x * a.x + a.y * a.y + a.z * a.z) / m.x
                         + (a.w * a.w + c.x * c.x + c.y * c.y) / m.y
                         + (c.z * c.z + c.w * c.w + d.x * d.x) / m.z
                         + (d.y * d.y + d.z * d.z + d.w * d.w) / m.w;
                }
                t = acc;
            }
        }
        #pragma unroll
        for (int off = 32; off > 0; off >>= 1) t += __shfl_down(t, off, 64);

        if (threadIdx.x == 0) {
            float kin = t;
            constexpr double W1 = 0.78451361047756;
            constexpr double W2 = 0.235573213359357;
            constexpr double W3 = -1.17767998417887;
            constexpr double W4 = 1.0 - 2.0 * (W1 + W2 + W3);
            const float syw[7] = {(float)W1, (float)W2, (float)W3, (float)W4,
                                  (float)W3, (float)W2, (float)W1};

            const float kb = kbt[b], dt = dtm[b], st = stp[0];
            float pnh[NCH], mnh[NCH], qn[NCH];
            #pragma unroll
            for (int c = 0; c < NCH; ++c) {
                pnh[c] = pos_nhc[b * NCH + c];
                mnh[c] = mom_nhc[b * NCH + c];
                qn[c]  = mas_nhc[b * NCH + c];
            }

            float Scum = 1.0f;
            for (int r = 0; r < 14; ++r) {        // NRESPA(2) x 7 SY weights
                const float w   = syw[r % 7];
                const float dea = dt * (st * w * 0.5f);
                const float de2 = dea * 0.5f;
                const float de4 = dea * 0.25f;

                float gg[NCH], mc[NCH];
                gg[0] = kin - kb * dof;
                #pragma unroll
                for (int j = 1; j < NCH; ++j)
                    gg[j] = mnh[j - 1] * mnh[j - 1] / qn[j - 1] - kb;
                #pragma unroll
                for (int c = 0; c < NCH; ++c) mc[c] = mnh[c];

                // first half-kick + chain pass (pre-step g)
                mc[NCH - 1] += gg[NCH - 1] * de2;
                #pragma unroll
                for (int j = NCH - 2; j >= 0; --j) {
                    const float f = expf(-mc[j + 1] / qn[j + 1] * de4);
                    mc[j] = (mc[j] * f + gg[j] * de2) * f;
                }

                // drift + momentum rescale (carried algebraically on kin)
                #pragma unroll
                for (int c = 0; c < NCH; ++c) pnh[c] += mc[c] / qn[c] * dea;
                const float s = expf(-mc[0] / qn[0] * dea);
                Scum *= s;
                kin  *= s * s;   // sum((s*mom)^2/mas) == s^2 * KE

                // second half: g0 from rescaled KE; g[1..] unchanged
                gg[0] = kin - kb * dof;
                #pragma unroll
                for (int j = NCH - 2; j >= 0; --j) {
                    const float f = expf(-mc[j + 1] / qn[j + 1] * de4);
                    mc[j] = (mc[j] * f + gg[j] * de2) * f;
                }
                mc[NCH - 1] += gg[NCH - 1] * de2;

                #pragma unroll
                for (int c = 0; c < NCH; ++c) mnh[c] = mc[c];
            }

            s_scale = Scum;
            if (x == 0) {
                #pragma unroll
                for (int c = 0; c < NCH; ++c) {
                    out_posnhc[b * NCH + c] = pnh[c];
                    out_momnhc[b * NCH + c] = mnh[c];
                }
            }
        }
    }
    __syncthreads();

    // ---- Phase C: scale held registers, store once ----
    const float s = s_scale;
    float4* o4 = (float4*)out_mom + (size_t)b * n4_per_batch + 12 * (size_t)g;
    #pragma unroll
    for (int k = 0; k < 12; ++k) {
        float4 v = P[k];
        v.x *= s; v.y *= s; v.z *= s; v.w *= s;
        o4[k] = v;
    }
}

extern "C" void kernel_launch(void* const* d_in, const int* in_sizes, int n_in,
                              void* d_out, int out_size, void* d_ws, size_t ws_size,
                              hipStream_t stream) {
    // input order: pos(0, unused), mom(1), mas(2), kbt(3), dtm(4),
    //              pos_nhc(5), mom_nhc(6), mas_nhc(7), stp(8)
    const float* mom     = (const float*)d_in[1];
    const float* mas     = (const float*)d_in[2];
    const float* kbt     = (const float*)d_in[3];
    const float* dtm     = (const float*)d_in[4];
    const float* pos_nhc = (const float*)d_in[5];
    const float* mom_nhc = (const float*)d_in[6];
    const float* mas_nhc = (const float*)d_in[7];
    const float* stp     = (const float*)d_in[8];

    const int B  = in_sizes[3];            // 32
    const int ND = in_sizes[1] / B;        // N*D = 393216
    const int N  = in_sizes[2] / B;        // 131072 atoms
    (void)n_in; (void)ws_size; (void)out_size;
    const float dof = (float)ND;

    const int n4  = ND / 4;                // 98304 float4 of mom per batch
    const int nm4 = N / 4;                 // 32768 float4 of mas per batch

    unsigned int* sig_part = (unsigned int*)d_ws;          // 1024 u32
    unsigned int* sig_chk  = sig_part + 1024;              // 1024 u32

    float* out_f      = (float*)d_out;
    float* out_posnhc = out_f + (size_t)B * ND;
    float* out_momnhc = out_posnhc + (size_t)B * NCH;

    // 32 blocks/batch x 256 thr -> 8192 threads/batch -> exactly 12 float4
    // of mom and 4 float4 of mas per thread. Batch-major 1D grid.
    nhc_fused<<<dim3(32 * B), dim3(256), 0, stream>>>(
        mom, mas, kbt, dtm, pos_nhc, mom_nhc, mas_nhc, stp,
        out_f, out_posnhc, out_momnhc, sig_part, sig_chk, n4, nm4, dof);
}

// Round 4
// 177.251 us; speedup vs baseline: 1.3284x; 1.3284x over previous
//
#include <hip/hip_runtime.h>

#define NCH 5  // thermostat chain length (C) — fixed by the problem

// ---------------------------------------------------------------------------
// Two-kernel structure (verified at 176 us in round 0; the fused/cross-block
// variants of rounds 1-3 all failed or regressed -- see session journal).
//
// Kernel 1: per-batch KE reduction with FULLY-COALESCED loads.
//   Lane l, round r handles atom  base + r*256 + l  =>  mom is read as
//   float3 at 12 B lane stride and mas as float at 4 B lane stride --
//   every wave-load's 64 lanes are contiguous (no request amplification;
//   round-0's 48 B-stride float4 pattern cost ~3x line requests).
//   8 atoms/thread, 2048-atom block tile, 64 blocks/batch.
// ---------------------------------------------------------------------------
__global__ __launch_bounds__(256) void nhc_reduce(
    const float* __restrict__ mom, const float* __restrict__ mas,
    float* __restrict__ partials, int n_atoms, int nd)
{
    const int b    = blockIdx.y;
    const int base = blockIdx.x * 2048;
    const float* momb = mom + (size_t)b * nd;
    const float* masb = mas + (size_t)b * n_atoms;

    float ke = 0.0f;
    #pragma unroll
    for (int r = 0; r < 8; ++r) {
        const int a = base + r * 256 + threadIdx.x;
        const float3 p = *(const float3*)(momb + 3 * (size_t)a);
        const float  m = masb[a];
        ke += (p.x * p.x + p.y * p.y + p.z * p.z) / m;
    }

    // deterministic block reduce: fixed butterfly + fixed wave order
    #pragma unroll
    for (int off = 32; off > 0; off >>= 1) ke += __shfl_down(ke, off, 64);
    __shared__ float lds[4];
    const int lane = threadIdx.x & 63, wv = threadIdx.x >> 6;
    if (lane == 0) lds[wv] = ke;
    __syncthreads();
    if (threadIdx.x == 0)
        partials[(size_t)b * gridDim.x + blockIdx.x] =
            lds[0] + lds[1] + lds[2] + lds[3];
}

// ---------------------------------------------------------------------------
// Kernel 2: fused chain + scale. Changes vs round 0:
//  (a) the 6 float4 mom loads are issued BEFORE the chain prelude, so their
//      HBM/L3 latency hides under the ~serial 14-substep chain (waves 1-3
//      park at the barrier with loads already in flight);
//  (b) __expf (v_exp_f32) in the chain: args are O(1e-3), absolute error
//      ~1e-7 -- three orders below the harness threshold; prelude ~3x faster.
// Every block redundantly computes the chain (bit-identical); block x==0
// writes pos_nhc / mom_nhc.
// ---------------------------------------------------------------------------
__global__ __launch_bounds__(256) void nhc_chain_scale(
    const float* __restrict__ mom, const float* __restrict__ partials,
    const float* __restrict__ kbt, const float* __restrict__ dtm,
    const float* __restrict__ pos_nhc, const float* __restrict__ mom_nhc,
    const float* __restrict__ mas_nhc, const float* __restrict__ stp,
    float* __restrict__ out_mom, float* __restrict__ out_posnhc,
    float* __restrict__ out_momnhc,
    int bpb_red, int n4_per_batch, float dof)
{
    const int b   = blockIdx.y;
    const int tid = threadIdx.x;
    const float4* in4 = (const float4*)mom   + (size_t)b * n4_per_batch;
    float4*       o4  = (float4*)out_mom     + (size_t)b * n4_per_batch;
    const int i0     = blockIdx.x * 256 + tid;
    const int stride = gridDim.x * 256;      // 16384 for the 64x256 launch

    // ---- issue data loads first (latency hides under the chain) ----
    const bool fast = (6 * stride == n4_per_batch);
    float4 v0, v1, v2, v3, v4, v5;
    if (fast) {
        v0 = in4[i0];
        v1 = in4[i0 + 1 * stride];
        v2 = in4[i0 + 2 * stride];
        v3 = in4[i0 + 3 * stride];
        v4 = in4[i0 + 4 * stride];
        v5 = in4[i0 + 5 * stride];
    }

    __shared__ float s_scale;

    // ---- wave-0 prelude: partials reduce + redundant SY chain ----
    if (tid < 64) {
        float t = 0.0f;
        for (int i = tid; i < bpb_red; i += 64)
            t += partials[(size_t)b * bpb_red + i];
        #pragma unroll
        for (int off = 32; off > 0; off >>= 1) t += __shfl_down(t, off, 64);

        if (tid == 0) {
            float kin = t;
            constexpr double W1 = 0.78451361047756;
            constexpr double W2 = 0.235573213359357;
            constexpr double W3 = -1.17767998417887;
            constexpr double W4 = 1.0 - 2.0 * (W1 + W2 + W3);
            const float syw[7] = {(float)W1, (float)W2, (float)W3, (float)W4,
                                  (float)W3, (float)W2, (float)W1};

            const float kb = kbt[b], dt = dtm[b], st = stp[0];
            float pnh[NCH], mnh[NCH], qn[NCH];
            #pragma unroll
            for (int c = 0; c < NCH; ++c) {
                pnh[c] = pos_nhc[b * NCH + c];
                mnh[c] = mom_nhc[b * NCH + c];
                qn[c]  = mas_nhc[b * NCH + c];
            }

            float Scum = 1.0f;
            for (int r = 0; r < 14; ++r) {        // NRESPA(2) x 7 SY weights
                const float w   = syw[r % 7];
                const float dea = dt * (st * w * 0.5f);
                const float de2 = dea * 0.5f;
                const float de4 = dea * 0.25f;

                float gg[NCH], mc[NCH];
                gg[0] = kin - kb * dof;
                #pragma unroll
                for (int j = 1; j < NCH; ++j)
                    gg[j] = mnh[j - 1] * mnh[j - 1] / qn[j - 1] - kb;
                #pragma unroll
                for (int c = 0; c < NCH; ++c) mc[c] = mnh[c];

                // first half-kick + chain pass (pre-step g)
                mc[NCH - 1] += gg[NCH - 1] * de2;
                #pragma unroll
                for (int j = NCH - 2; j >= 0; --j) {
                    const float f = __expf(-mc[j + 1] / qn[j + 1] * de4);
                    mc[j] = (mc[j] * f + gg[j] * de2) * f;
                }

                // drift + momentum rescale (carried algebraically on kin)
                #pragma unroll
                for (int c = 0; c < NCH; ++c) pnh[c] += mc[c] / qn[c] * dea;
                const float s = __expf(-mc[0] / qn[0] * dea);
                Scum *= s;
                kin  *= s * s;   // sum((s*mom)^2/mas) == s^2 * KE

                // second half: g0 from rescaled KE; g[1..] unchanged
                gg[0] = kin - kb * dof;
                #pragma unroll
                for (int j = NCH - 2; j >= 0; --j) {
                    const float f = __expf(-mc[j + 1] / qn[j + 1] * de4);
                    mc[j] = (mc[j] * f + gg[j] * de2) * f;
                }
                mc[NCH - 1] += gg[NCH - 1] * de2;

                #pragma unroll
                for (int c = 0; c < NCH; ++c) mnh[c] = mc[c];
            }

            s_scale = Scum;
            if (blockIdx.x == 0) {
                #pragma unroll
                for (int c = 0; c < NCH; ++c) {
                    out_posnhc[b * NCH + c] = pnh[c];
                    out_momnhc[b * NCH + c] = mnh[c];
                }
            }
        }
    }
    __syncthreads();

    // ---- scale + store ----
    const float s = s_scale;
    if (fast) {
        v0.x *= s; v0.y *= s; v0.z *= s; v0.w *= s; o4[i0]              = v0;
        v1.x *= s; v1.y *= s; v1.z *= s; v1.w *= s; o4[i0 + 1 * stride] = v1;
        v2.x *= s; v2.y *= s; v2.z *= s; v2.w *= s; o4[i0 + 2 * stride] = v2;
        v3.x *= s; v3.y *= s; v3.z *= s; v3.w *= s; o4[i0 + 3 * stride] = v3;
        v4.x *= s; v4.y *= s; v4.z *= s; v4.w *= s; o4[i0 + 4 * stride] = v4;
        v5.x *= s; v5.y *= s; v5.z *= s; v5.w *= s; o4[i0 + 5 * stride] = v5;
    } else {
        for (int i = i0; i < n4_per_batch; i += stride) {
            float4 v = in4[i];
            v.x *= s; v.y *= s; v.z *= s; v.w *= s;
            o4[i] = v;
        }
    }
}

extern "C" void kernel_launch(void* const* d_in, const int* in_sizes, int n_in,
                              void* d_out, int out_size, void* d_ws, size_t ws_size,
                              hipStream_t stream) {
    // input order: pos(0, unused), mom(1), mas(2), kbt(3), dtm(4),
    //              pos_nhc(5), mom_nhc(6), mas_nhc(7), stp(8)
    const float* mom     = (const float*)d_in[1];
    const float* mas     = (const float*)d_in[2];
    const float* kbt     = (const float*)d_in[3];
    const float* dtm     = (const float*)d_in[4];
    const float* pos_nhc = (const float*)d_in[5];
    const float* mom_nhc = (const float*)d_in[6];
    const float* mas_nhc = (const float*)d_in[7];
    const float* stp     = (const float*)d_in[8];

    const int B  = in_sizes[3];            // 32
    const int ND = in_sizes[1] / B;        // N*D = 393216
    const int N  = in_sizes[2] / B;        // 131072 atoms
    (void)n_in; (void)ws_size; (void)out_size;
    const float dof = (float)ND;

    const int blocks_per_batch = N / 2048;   // 64 (N % 2048 == 0 by problem)

    float* partials = (float*)d_ws;          // B * 64 floats

    float* out_f      = (float*)d_out;
    float* out_posnhc = out_f + (size_t)B * ND;
    float* out_momnhc = out_posnhc + (size_t)B * NCH;

    nhc_reduce<<<dim3(blocks_per_batch, B), 256, 0, stream>>>(
        mom, mas, partials, N, ND);

    const int n4 = ND / 4;                   // 98304 float4 per batch
    nhc_chain_scale<<<dim3(64, B), 256, 0, stream>>>(
        mom, partials, kbt, dtm, pos_nhc, mom_nhc, mas_nhc, stp,
        out_f, out_posnhc, out_momnhc, blocks_per_batch, n4, dof);
}